// Round 12
// baseline (289.297 us; speedup 1.0000x reference)
//
#include <hip/hip_runtime.h>
#include <hip/hip_cooperative_groups.h>

namespace cg = cooperative_groups;

#define ND 2048
#define NM 512
#define DIN 256
#define OC 128
#define NTOT 2560
#define NE 513      // slots per hyperedge
#define NB 256      // grid blocks (1 per CU -> co-resident)

// Workspace float offsets (total 564,736 floats = 2.26 MB)
#define WS_MEANC 0
#define WS_MEANM 256
#define WS_WE    512
#define WS_DIA   768
#define WS_MED   896
#define WS_AHE   1024                    // [2048]
#define WS_ANODE 3072                    // [2560]
#define WS_CD    5632                    // [2048]
#define WS_PARTC 7680                    // [256*256]
#define WS_PARTM (WS_PARTC + 256*256)    // [256*256]
#define WS_PARTW (WS_PARTM + 256*256)    // [128*256]
#define WS_XLIN  (WS_PARTW + 128*256)    // [2560*128]; disease rows -> e in P2
#define WS_PART2 (WS_XLIN + NTOT*OC)     // [32*8*16*128]

__device__ __forceinline__ float lrelu(float x) { return x > 0.f ? x : 0.2f * x; }

__global__ void __launch_bounds__(256, 1) kFused(
        const float* __restrict__ c_emb, const float* __restrict__ m_emb,
        const float* __restrict__ W_conv, const float* __restrict__ b_conv,
        const float* __restrict__ W_gat, const float* __restrict__ att,
        const float* __restrict__ b_gat, const float* __restrict__ he_attr,
        float* __restrict__ ws, float* __restrict__ out) {
    cg::grid_group grid = cg::this_grid();
    __shared__ float smem[6400];   // 25.6 KB, reused across phases
    const int b = blockIdx.x, t = threadIdx.x;

    //========== P0: x_lin + a_node (10 rows/block) + mean/we partials ==========
    {
        // mean partials (coalesced row-major)
        float sc = 0.f;
        const float* srcc = c_emb + (size_t)b * 8 * DIN;
#pragma unroll
        for (int r = 0; r < 8; ++r) sc += srcc[r * DIN + t];
        ws[WS_PARTC + b * 256 + t] = sc;
        ws[WS_PARTM + b * 256 + t] = m_emb[(size_t)(2 * b) * DIN + t]
                                   + m_emb[(size_t)(2 * b + 1) * DIN + t];
        if (b < OC) ws[WS_PARTW + b * 256 + t] = W_gat[(size_t)b * DIN + t] * att[OC + b];

        // x_lin rows d0..d0+9
        float (*row)[DIN] = (float(*)[DIN])smem;             // 10*256
        float (*sA)[OC]   = (float(*)[OC])(smem + 10 * DIN); // 10*128
        const int d0 = b * 10;
#pragma unroll
        for (int p = 0; p < 5; ++p) {
            const int r = 2 * p + (t >> 7);
            const int d = d0 + r;
            const float* src = (d < ND) ? c_emb + (size_t)d * DIN
                                        : m_emb + (size_t)(d - ND) * DIN;
            float2 u = ((const float2*)src)[t & 127];
            row[r][2 * (t & 127)]     = u.x;
            row[r][2 * (t & 127) + 1] = u.y;
        }
        __syncthreads();
        const int o = t & (OC - 1), h = t >> 7;
        float acc[5] = {0.f, 0.f, 0.f, 0.f, 0.f};
        const float4* wr = (const float4*)(W_gat + (size_t)o * DIN);
        for (int v = 0; v < 64; ++v) {
            const float4 w = wr[v];
            const int ib = 4 * v;
#pragma unroll
            for (int k = 0; k < 5; ++k) {
                const float* rw = row[5 * h + k] + ib;
                acc[k] = fmaf(rw[0], w.x, acc[k]);
                acc[k] = fmaf(rw[1], w.y, acc[k]);
                acc[k] = fmaf(rw[2], w.z, acc[k]);
                acc[k] = fmaf(rw[3], w.w, acc[k]);
            }
        }
        const float at = att[o];
#pragma unroll
        for (int k = 0; k < 5; ++k) {
            ws[WS_XLIN + (size_t)(d0 + 5 * h + k) * OC + o] = acc[k];
            sA[5 * h + k][o] = acc[k] * at;
        }
        __syncthreads();
#pragma unroll
        for (int st = 64; st >= 1; st >>= 1) {
            for (int idx = t; idx < 10 * st; idx += 256) {
                const int r = idx / st, i = idx - r * st;
                sA[r][i] += sA[r][i + st];
            }
            __syncthreads();
        }
        if (t < 10) ws[WS_ANODE + d0 + t] = sA[t][0];
    }
    grid.sync();

    //========== P1: combine partials -> means/we; dia/med vectors ==========
    if (b == 0) {
        float sc = 0.f, sm = 0.f, sw = 0.f;
        for (int bb = 0; bb < 256; ++bb) sc += ws[WS_PARTC + bb * 256 + t];
        for (int bb = 0; bb < 256; ++bb) sm += ws[WS_PARTM + bb * 256 + t];
        for (int bb = 0; bb < 128; ++bb) sw += ws[WS_PARTW + bb * 256 + t];
        ws[WS_MEANC + t] = sc * (1.f / ND);
        ws[WS_MEANM + t] = sm * (1.f / NM);
        ws[WS_WE + t]    = sw;
        __syncthreads();
        if (t < OC) {
            const float* wrr = W_conv + (size_t)t * DIN;
            float a = 0.f, m2 = 0.f;
            for (int i = 0; i < DIN; ++i) {
                const float w = wrr[i];
                a  = fmaf(ws[WS_MEANC + i], w, a);
                m2 = fmaf(ws[WS_MEANM + i], w, m2);
            }
            const float bc = b_conv[t];
            ws[WS_DIA + t] = a + bc;
            ws[WS_MED + t] = m2 + bc;
        }
    }
    grid.sync();

    //========== P2: 8 hyperedges/block: a_he, softmax, e, disease rows ==========
    {
        float (*zbuf)[8] = (float(*)[8])smem;                 // [NE][8] = 4104
        float* anm  = smem + 4112;                            // [512]
        float (*ec)[OC] = (float(*)[OC])(smem + 4112 + 512);  // [8][128]
        float* sinv = smem + 4112 + 512 + 8 * OC;             // [8]
        anm[t]       = ws[WS_ANODE + ND + t];
        anm[t + 256] = ws[WS_ANODE + ND + 256 + t];
        __syncthreads();
        const int r = t >> 5, l = t & 31;
        const int d = b * 8 + r;
        // a_he[d] = he_attr[d,:] . w_e  (32-lane group)
        const float* he = he_attr + (size_t)d * DIN;
        float ah = 0.f;
        for (int i = l; i < DIN; i += 32) ah = fmaf(he[i], ws[WS_WE + i], ah);
#pragma unroll
        for (int m = 1; m < 32; m <<= 1) ah += __shfl_xor(ah, m, 32);
        if (l == 0) ws[WS_AHE + d] = ah;
        // softmax over 513 slots
        const float an_d = ws[WS_ANODE + d];
        float lmax = -3.4e38f;
        for (int j = l; j < NE; j += 32) {
            const float v = (j == 0) ? an_d : anm[j - 1];
            const float lg = lrelu(v + ah);
            zbuf[j][r] = lg;
            lmax = fmaxf(lmax, lg);
        }
#pragma unroll
        for (int m = 1; m < 32; m <<= 1) lmax = fmaxf(lmax, __shfl_xor(lmax, m, 32));
        float ss = 0.f;
        for (int j = l; j < NE; j += 32) {
            const float z = __expf(zbuf[j][r] - lmax);
            zbuf[j][r] = z;
            ss += z;
        }
#pragma unroll
        for (int m = 1; m < 32; m <<= 1) ss += __shfl_xor(ss, m, 32);
        if (l == 0) { sinv[r] = 1.f / ss; ws[WS_CD + d] = lmax + __logf(ss); }
        __syncthreads();
        // Phase B: acc[k] = sum_j zbuf[j+1][k] * Xm[j][o]
        const int o = t & (OC - 1), h = t >> 7;
        float acc[8] = {0, 0, 0, 0, 0, 0, 0, 0};
        const float* xm = ws + WS_XLIN + (size_t)ND * OC;
        for (int j = h * 256; j < h * 256 + 256; ++j) {
            const float xv = xm[(size_t)j * OC + o];
            const float4* zr = (const float4*)zbuf[j + 1];
            const float4 za = zr[0], zb4 = zr[1];
            acc[0] = fmaf(za.x,  xv, acc[0]);
            acc[1] = fmaf(za.y,  xv, acc[1]);
            acc[2] = fmaf(za.z,  xv, acc[2]);
            acc[3] = fmaf(za.w,  xv, acc[3]);
            acc[4] = fmaf(zb4.x, xv, acc[4]);
            acc[5] = fmaf(zb4.y, xv, acc[5]);
            acc[6] = fmaf(zb4.z, xv, acc[6]);
            acc[7] = fmaf(zb4.w, xv, acc[7]);
        }
        if (h == 1) {
#pragma unroll
            for (int k = 0; k < 8; ++k) ec[k][o] = acc[k];
        }
        __syncthreads();
        if (h == 0) {
            const float bg = b_gat[o];
            const float dv = ws[WS_DIA + o];
#pragma unroll
            for (int k = 0; k < 8; ++k) {
                const int dd = b * 8 + k;
                const float inv = sinv[k];
                const float z0 = zbuf[0][k];
                const float xown = ws[WS_XLIN + (size_t)dd * OC + o];
                const float ev = fmaf(z0, xown, acc[k] + ec[k][o]) * inv * (1.f / NE);
                ws[WS_XLIN + (size_t)dd * OC + o] = ev;   // e in-place
                out[(size_t)dd * 2 * OC + o]      = fmaf(z0 * inv, ev, bg);
                out[(size_t)dd * 2 * OC + OC + o] = dv;
            }
        }
    }
    grid.sync();

    //========== P3: kE partials (16 medicines x 256 diseases per block) ==========
    {
        const int g = b >> 3, c = b & 7;
        float (*zb)[16]  = (float(*)[16])smem;              // [256][16]
        float (*ec2)[OC] = (float(*)[OC])(smem + 4096);     // [16][128]
        for (int idx = t; idx < 4096; idx += 256) {
            const int mi = idx & 15, dd = idx >> 4;
            const int d = c * 256 + dd;
            zb[dd][mi] = __expf(lrelu(ws[WS_ANODE + ND + g * 16 + mi] + ws[WS_AHE + d])
                                - ws[WS_CD + d]);
        }
        __syncthreads();
        const int o = t & (OC - 1), h = t >> 7;
        float acc[16];
#pragma unroll
        for (int k = 0; k < 16; ++k) acc[k] = 0.f;
        const float* e = ws + WS_XLIN;
        for (int dd = h * 128; dd < h * 128 + 128; ++dd) {
            const float ev = e[(size_t)(c * 256 + dd) * OC + o];
            const float4* zr = (const float4*)zb[dd];
            const float4 z0 = zr[0], z1 = zr[1], z2 = zr[2], z3 = zr[3];
            acc[0]  = fmaf(z0.x, ev, acc[0]);   acc[1]  = fmaf(z0.y, ev, acc[1]);
            acc[2]  = fmaf(z0.z, ev, acc[2]);   acc[3]  = fmaf(z0.w, ev, acc[3]);
            acc[4]  = fmaf(z1.x, ev, acc[4]);   acc[5]  = fmaf(z1.y, ev, acc[5]);
            acc[6]  = fmaf(z1.z, ev, acc[6]);   acc[7]  = fmaf(z1.w, ev, acc[7]);
            acc[8]  = fmaf(z2.x, ev, acc[8]);   acc[9]  = fmaf(z2.y, ev, acc[9]);
            acc[10] = fmaf(z2.z, ev, acc[10]);  acc[11] = fmaf(z2.w, ev, acc[11]);
            acc[12] = fmaf(z3.x, ev, acc[12]);  acc[13] = fmaf(z3.y, ev, acc[13]);
            acc[14] = fmaf(z3.z, ev, acc[14]);  acc[15] = fmaf(z3.w, ev, acc[15]);
        }
        if (h == 1) {
#pragma unroll
            for (int k = 0; k < 16; ++k) ec2[k][o] = acc[k];
        }
        __syncthreads();
        if (h == 0) {
            float* part = ws + WS_PART2 + (size_t)(g * 8 + c) * 16 * OC;
#pragma unroll
            for (int k = 0; k < 16; ++k) part[k * OC + o] = acc[k] + ec2[k][o];
        }
    }
    grid.sync();

    //========== P4: reduce partials, medicine output rows ==========
    {
        const int o = t & (OC - 1);
        const int m = 2 * b + (t >> 7);
        const int g = m >> 4, k = m & 15;
        float s = 0.f;
#pragma unroll
        for (int c = 0; c < 8; ++c)
            s += ws[WS_PART2 + ((size_t)(g * 8 + c) * 16 + k) * OC + o];
        out[(size_t)(ND + m) * 2 * OC + o]      = fmaf(s, 1.f / ND, b_gat[o]);
        out[(size_t)(ND + m) * 2 * OC + OC + o] = ws[WS_MED + o];
    }
}

extern "C" void kernel_launch(void* const* d_in, const int* in_sizes, int n_in,
                              void* d_out, int out_size, void* d_ws, size_t ws_size,
                              hipStream_t stream) {
    const float* c_emb   = (const float*)d_in[2];
    const float* m_emb   = (const float*)d_in[3];
    const float* W_conv  = (const float*)d_in[4];
    const float* b_conv  = (const float*)d_in[5];
    const float* W_gat   = (const float*)d_in[6];
    const float* att     = (const float*)d_in[7];
    const float* b_gat   = (const float*)d_in[8];
    const float* he_attr = (const float*)d_in[9];
    float* ws  = (float*)d_ws;
    float* out = (float*)d_out;

    void* args[] = { &c_emb, &m_emb, &W_conv, &b_conv, &W_gat,
                     &att, &b_gat, &he_attr, &ws, &out };
    hipLaunchCooperativeKernel((const void*)kFused, dim3(NB), dim3(256),
                               args, 0, stream);
}

// Round 13
// 219.991 us; speedup vs baseline: 1.3150x; 1.3150x over previous
//
#include <hip/hip_runtime.h>

#define ND 2048
#define NM 512
#define DIN 256
#define OC 128
#define NTOT 2560
#define NE 513      // slots per hyperedge
#define NB 256      // grid blocks (co-resident via cooperative launch)

// Workspace float offsets (total ~2 MB; ws is ~268 MB so plenty).
#define WS_BAR   0                        // [16] u32 barrier counters (memset to 0 each launch)
#define WS_AHE   64                       // [2048]
#define WS_ANODE (WS_AHE + ND)            // [2560]
#define WS_CD    (WS_ANODE + NTOT)        // [2048]
#define WS_PARTC (WS_CD + ND)             // [256*256]
#define WS_PARTM (WS_PARTC + 256*256)     // [256*256]
#define WS_PARTW (WS_PARTM + 256*256)     // [128*256]
#define WS_XLIN  (WS_PARTW + 128*256)     // [2560*128]; disease rows -> e in P2

__device__ __forceinline__ float lrelu(float x) { return x > 0.f ? x : 0.2f * x; }

// Lightweight grid barrier: ~64-cycle poll vs cg's s_sleep(127) backoff.
__device__ __forceinline__ void gbar(unsigned* ctr) {
    __syncthreads();
    if (threadIdx.x == 0) {
        __threadfence();  // release: make this block's ws/out writes visible device-wide
        __hip_atomic_fetch_add(ctr, 1u, __ATOMIC_RELEASE, __HIP_MEMORY_SCOPE_AGENT);
        while (__hip_atomic_load(ctr, __ATOMIC_ACQUIRE, __HIP_MEMORY_SCOPE_AGENT) < NB)
            __builtin_amdgcn_s_sleep(1);
        __threadfence();  // acquire: invalidate L1 so post-barrier reads are fresh
    }
    __syncthreads();
}

__global__ void __launch_bounds__(256, 1) kFused(
        const float* __restrict__ c_emb, const float* __restrict__ m_emb,
        const float* __restrict__ W_conv, const float* __restrict__ b_conv,
        const float* __restrict__ W_gat, const float* __restrict__ att,
        const float* __restrict__ b_gat, const float* __restrict__ he_attr,
        float* __restrict__ ws, float* __restrict__ out) {
    const int b = blockIdx.x, t = threadIdx.x;
    __shared__ float dia[OC], med[OC], sahe[8];  // persist across phases
    __shared__ float smem[6400];                 // 25.6 KB scratch, reused per phase
    unsigned* bar = (unsigned*)ws;

    //========== P0: x_lin (10 rows/block) + a_node + mean/we partials ==========
    {
        float sc = 0.f;
        const float* srcc = c_emb + (size_t)b * 8 * DIN;
#pragma unroll
        for (int r = 0; r < 8; ++r) sc += srcc[r * DIN + t];
        ws[WS_PARTC + b * 256 + t] = sc;
        ws[WS_PARTM + b * 256 + t] = m_emb[(size_t)(2 * b) * DIN + t]
                                   + m_emb[(size_t)(2 * b + 1) * DIN + t];
        if (b < OC) ws[WS_PARTW + b * 256 + t] = W_gat[(size_t)b * DIN + t] * att[OC + b];

        float (*row)[DIN] = (float(*)[DIN])smem;             // 10*256
        float (*sA)[OC]   = (float(*)[OC])(smem + 10 * DIN); // 10*128
        const int d0 = b * 10;
#pragma unroll
        for (int p = 0; p < 5; ++p) {
            const int r = 2 * p + (t >> 7);
            const int d = d0 + r;
            const float* src = (d < ND) ? c_emb + (size_t)d * DIN
                                        : m_emb + (size_t)(d - ND) * DIN;
            float2 u = ((const float2*)src)[t & 127];
            row[r][2 * (t & 127)]     = u.x;
            row[r][2 * (t & 127) + 1] = u.y;
        }
        __syncthreads();
        const int o = t & (OC - 1), h = t >> 7;
        float acc[5] = {0.f, 0.f, 0.f, 0.f, 0.f};
        const float4* wr = (const float4*)(W_gat + (size_t)o * DIN);
        for (int v = 0; v < 64; ++v) {
            const float4 w = wr[v];
            const int ib = 4 * v;
#pragma unroll
            for (int k = 0; k < 5; ++k) {
                const float* rw = row[5 * h + k] + ib;
                acc[k] = fmaf(rw[0], w.x, acc[k]);
                acc[k] = fmaf(rw[1], w.y, acc[k]);
                acc[k] = fmaf(rw[2], w.z, acc[k]);
                acc[k] = fmaf(rw[3], w.w, acc[k]);
            }
        }
        const float at = att[o];
#pragma unroll
        for (int k = 0; k < 5; ++k) {
            ws[WS_XLIN + (size_t)(d0 + 5 * h + k) * OC + o] = acc[k];
            sA[5 * h + k][o] = acc[k] * at;
        }
        __syncthreads();
#pragma unroll
        for (int st = 64; st >= 1; st >>= 1) {
            for (int idx = t; idx < 10 * st; idx += 256) {
                const int r = idx / st, i = idx - r * st;
                sA[r][i] += sA[r][i + st];
            }
            __syncthreads();
        }
        if (t < 10) ws[WS_ANODE + d0 + t] = sA[t][0];
    }
    gbar(bar + 0);

    //========== P1 (redundant per block): means/we combine, dia/med, own a_he ==========
    {
        float* mc = smem;        // [256]
        float* mm = smem + 256;  // [256]
        float* we = smem + 512;  // [256]
        float sc = 0.f, sm = 0.f, sw = 0.f;
        for (int bb = 0; bb < 256; ++bb) sc += ws[WS_PARTC + bb * 256 + t];
        for (int bb = 0; bb < 256; ++bb) sm += ws[WS_PARTM + bb * 256 + t];
        for (int bb = 0; bb < 128; ++bb) sw += ws[WS_PARTW + bb * 256 + t];
        mc[t] = sc * (1.f / ND);
        mm[t] = sm * (1.f / NM);
        we[t] = sw;
        __syncthreads();
        if (t < OC) {
            const float* wrr = W_conv + (size_t)t * DIN;
            float a = 0.f, m2 = 0.f;
            for (int i = 0; i < DIN; ++i) {
                const float w = wrr[i];
                a  = fmaf(mc[i], w, a);
                m2 = fmaf(mm[i], w, m2);
            }
            const float bc = b_conv[t];
            dia[t] = a + bc;
            med[t] = m2 + bc;
        }
        // a_he for this block's 8 hyperedges
        const int r = t >> 5, l = t & 31;
        const int d = b * 8 + r;
        const float* he = he_attr + (size_t)d * DIN;
        float ah = 0.f;
        for (int i = l; i < DIN; i += 32) ah = fmaf(he[i], we[i], ah);
#pragma unroll
        for (int m = 1; m < 32; m <<= 1) ah += __shfl_xor(ah, m, 32);
        if (l == 0) { sahe[r] = ah; ws[WS_AHE + d] = ah; }
        __syncthreads();  // smem reused next phase
    }

    //========== P2: 8 hyperedges/block: softmax, e, disease rows ==========
    {
        float (*zbuf)[8] = (float(*)[8])smem;                 // [513][8]
        float* anm  = smem + 4112;                            // [512]
        float (*ec)[OC] = (float(*)[OC])(smem + 4624);        // [8][128]
        float* sinv = smem + 5648;                            // [8]
        anm[t]       = ws[WS_ANODE + ND + t];
        anm[t + 256] = ws[WS_ANODE + ND + 256 + t];
        __syncthreads();
        const int r = t >> 5, l = t & 31;
        const int d = b * 8 + r;
        const float ah = sahe[r];
        const float an_d = ws[WS_ANODE + d];
        float lmax = -3.4e38f;
        for (int j = l; j < NE; j += 32) {
            const float v = (j == 0) ? an_d : anm[j - 1];
            const float lg = lrelu(v + ah);
            zbuf[j][r] = lg;
            lmax = fmaxf(lmax, lg);
        }
#pragma unroll
        for (int m = 1; m < 32; m <<= 1) lmax = fmaxf(lmax, __shfl_xor(lmax, m, 32));
        float ss = 0.f;
        for (int j = l; j < NE; j += 32) {
            const float z = __expf(zbuf[j][r] - lmax);
            zbuf[j][r] = z;
            ss += z;
        }
#pragma unroll
        for (int m = 1; m < 32; m <<= 1) ss += __shfl_xor(ss, m, 32);
        if (l == 0) { sinv[r] = 1.f / ss; ws[WS_CD + d] = lmax + __logf(ss); }
        __syncthreads();
        const int o = t & (OC - 1), h = t >> 7;
        float acc[8] = {0, 0, 0, 0, 0, 0, 0, 0};
        const float* xm = ws + WS_XLIN + (size_t)ND * OC;
        for (int j = h * 256; j < h * 256 + 256; ++j) {
            const float xv = xm[(size_t)j * OC + o];
            const float4* zr = (const float4*)zbuf[j + 1];
            const float4 za = zr[0], zb4 = zr[1];
            acc[0] = fmaf(za.x,  xv, acc[0]);
            acc[1] = fmaf(za.y,  xv, acc[1]);
            acc[2] = fmaf(za.z,  xv, acc[2]);
            acc[3] = fmaf(za.w,  xv, acc[3]);
            acc[4] = fmaf(zb4.x, xv, acc[4]);
            acc[5] = fmaf(zb4.y, xv, acc[5]);
            acc[6] = fmaf(zb4.z, xv, acc[6]);
            acc[7] = fmaf(zb4.w, xv, acc[7]);
        }
        if (h == 1) {
#pragma unroll
            for (int k = 0; k < 8; ++k) ec[k][o] = acc[k];
        }
        __syncthreads();
        if (h == 0) {
            const float bg = b_gat[o];
            const float dv = dia[o];
#pragma unroll
            for (int k = 0; k < 8; ++k) {
                const int dd = b * 8 + k;
                const float inv = sinv[k];
                const float z0 = zbuf[0][k];
                const float xown = ws[WS_XLIN + (size_t)dd * OC + o];
                const float ev = fmaf(z0, xown, acc[k] + ec[k][o]) * inv * (1.f / NE);
                ws[WS_XLIN + (size_t)dd * OC + o] = ev;   // e in-place (own rows only)
                out[(size_t)dd * 2 * OC + o]      = fmaf(z0 * inv, ev, bg);
                out[(size_t)dd * 2 * OC + OC + o] = dv;
            }
        }
    }
    gbar(bar + 1);

    //========== P3: 2 medicines/block over all 2048 diseases; medicine rows ==========
    {
        float (*zb)[2]   = (float(*)[2])smem;            // [2048][2]
        float (*ec2)[OC] = (float(*)[OC])(smem + 4096);  // [2][128]
        const int m0 = b * 2;
        const float an0 = ws[WS_ANODE + ND + m0];
        const float an1 = ws[WS_ANODE + ND + m0 + 1];
        for (int dd = t; dd < ND; dd += 256) {
            const float ahv = ws[WS_AHE + dd];
            const float cdv = ws[WS_CD + dd];
            zb[dd][0] = __expf(lrelu(an0 + ahv) - cdv);
            zb[dd][1] = __expf(lrelu(an1 + ahv) - cdv);
        }
        __syncthreads();
        const int o = t & (OC - 1), h = t >> 7;
        float a0 = 0.f, a1 = 0.f;
        const float* e = ws + WS_XLIN;
        for (int dd = h * 1024; dd < h * 1024 + 1024; ++dd) {
            const float ev = e[(size_t)dd * OC + o];
            a0 = fmaf(zb[dd][0], ev, a0);
            a1 = fmaf(zb[dd][1], ev, a1);
        }
        if (h == 1) { ec2[0][o] = a0; ec2[1][o] = a1; }
        __syncthreads();
        if (h == 0) {
            const float bg = b_gat[o];
            const float mv = med[o];
            out[(size_t)(ND + m0) * 2 * OC + o]          = fmaf(a0 + ec2[0][o], 1.f / ND, bg);
            out[(size_t)(ND + m0) * 2 * OC + OC + o]     = mv;
            out[(size_t)(ND + m0 + 1) * 2 * OC + o]      = fmaf(a1 + ec2[1][o], 1.f / ND, bg);
            out[(size_t)(ND + m0 + 1) * 2 * OC + OC + o] = mv;
        }
    }
}

extern "C" void kernel_launch(void* const* d_in, const int* in_sizes, int n_in,
                              void* d_out, int out_size, void* d_ws, size_t ws_size,
                              hipStream_t stream) {
    const float* c_emb   = (const float*)d_in[2];
    const float* m_emb   = (const float*)d_in[3];
    const float* W_conv  = (const float*)d_in[4];
    const float* b_conv  = (const float*)d_in[5];
    const float* W_gat   = (const float*)d_in[6];
    const float* att     = (const float*)d_in[7];
    const float* b_gat   = (const float*)d_in[8];
    const float* he_attr = (const float*)d_in[9];
    float* ws  = (float*)d_ws;
    float* out = (float*)d_out;

    // zero the barrier counters (ws is poisoned 0xAA before every launch)
    hipMemsetAsync(d_ws, 0, 64, stream);

    void* args[] = { &c_emb, &m_emb, &W_conv, &b_conv, &W_gat,
                     &att, &b_gat, &he_attr, &ws, &out };
    hipLaunchCooperativeKernel((const void*)kFused, dim3(NB), dim3(256),
                               args, 0, stream);
}

// Round 14
// 154.429 us; speedup vs baseline: 1.8733x; 1.4245x over previous
//
#include <hip/hip_runtime.h>

#define ND 2048
#define NM 512
#define DIN 256
#define OC 128
#define NTOT 2560
#define NE 513      // slots per hyperedge

// Workspace float offsets (total ~69 MB; ws is ~268 MB)
#define WS_PARTC 0                          // [512*256]
#define WS_PARTM (WS_PARTC + 512*256)       // [128*256]
#define WS_AHE   (WS_PARTM + 128*256)       // [2048]
#define WS_ANODE (WS_AHE + ND)              // [2560]
#define WS_XLIN  (WS_ANODE + NTOT)          // [2560*128]
#define WS_DIA   (WS_XLIN + NTOT*OC)        // [128]
#define WS_MED   (WS_DIA + OC)              // [128]
#define WS_PART2 (WS_MED + OC)              // [256*512*128] medicine partials

__device__ __forceinline__ float lrelu(float x) { return x > 0.f ? x : 0.2f * x; }

// ---------------------------------------------------------------------------
// K1: blocks 0..639: x_lin (4 rows) + a_node + mean partials (free from LDS rows).
//     blocks 640..895: w_e (coalesced, redundant per block) + a_he (8 d's each).
__global__ void __launch_bounds__(256) K1(
        const float* __restrict__ c_emb, const float* __restrict__ m_emb,
        const float* __restrict__ W_gat, const float* __restrict__ att,
        const float* __restrict__ he_attr, float* __restrict__ ws) {
    const int b = blockIdx.x, t = threadIdx.x;
    if (b < 640) {
        __shared__ float row[4][DIN];
        __shared__ float sA[4][OC];
        const int d0 = b * 4;
#pragma unroll
        for (int p = 0; p < 2; ++p) {
            const int idx = p * 256 + t;
            const int r = idx >> 7, c = idx & 127;
            const int d = d0 + r;
            const float* src = (d < ND) ? c_emb + (size_t)d * DIN
                                        : m_emb + (size_t)(d - ND) * DIN;
            const float2 u = ((const float2*)src)[c];
            row[r][2 * c]     = u.x;
            row[r][2 * c + 1] = u.y;
        }
        __syncthreads();
        // column partial of this block's 4 rows (for means)
        {
            const float pc = row[0][t] + row[1][t] + row[2][t] + row[3][t];
            if (b < 512) ws[WS_PARTC + b * 256 + t] = pc;
            else         ws[WS_PARTM + (b - 512) * 256 + t] = pc;
        }
        const int o = t & (OC - 1), h = t >> 7;
        float a0 = 0.f, a1 = 0.f;
        const float4* wr = (const float4*)(W_gat + (size_t)o * DIN);
        const float* r0 = row[2 * h];
        const float* r1 = row[2 * h + 1];
#pragma unroll 8
        for (int v = 0; v < 64; ++v) {
            const float4 w = wr[v];
            const int ib = 4 * v;
            a0 = fmaf(r0[ib],     w.x, a0);
            a0 = fmaf(r0[ib + 1], w.y, a0);
            a0 = fmaf(r0[ib + 2], w.z, a0);
            a0 = fmaf(r0[ib + 3], w.w, a0);
            a1 = fmaf(r1[ib],     w.x, a1);
            a1 = fmaf(r1[ib + 1], w.y, a1);
            a1 = fmaf(r1[ib + 2], w.z, a1);
            a1 = fmaf(r1[ib + 3], w.w, a1);
        }
        ws[WS_XLIN + (size_t)(d0 + 2 * h) * OC + o]     = a0;
        ws[WS_XLIN + (size_t)(d0 + 2 * h + 1) * OC + o] = a1;
        const float at = att[o];
        sA[2 * h][o]     = a0 * at;
        sA[2 * h + 1][o] = a1 * at;
        __syncthreads();
#pragma unroll
        for (int st = 64; st >= 1; st >>= 1) {
            if (t < 4 * st) {
                const int r = t / st, i = t - r * st;
                sA[r][i] += sA[r][i + st];
            }
            __syncthreads();
        }
        if (t < 4) ws[WS_ANODE + d0 + t] = sA[t][0];
    } else {
        // a_he block
        __shared__ float satt[OC];
        __shared__ float we[DIN];
        const int q = b - 640;
        if (t < OC) satt[t] = att[OC + t];
        __syncthreads();
        float acc = 0.f;
#pragma unroll 8
        for (int o = 0; o < OC; ++o)
            acc = fmaf(W_gat[(size_t)o * DIN + t], satt[o], acc);
        we[t] = acc;
        __syncthreads();
        const int r = t >> 5, l = t & 31;
        const int d = q * 8 + r;
        const float* he = he_attr + (size_t)d * DIN;
        float ah = 0.f;
#pragma unroll
        for (int i = l; i < DIN; i += 32) ah = fmaf(he[i], we[i], ah);
#pragma unroll
        for (int m = 1; m < 32; m <<= 1) ah += __shfl_xor(ah, m, 32);
        if (l == 0) ws[WS_AHE + d] = ah;
    }
}

// ---------------------------------------------------------------------------
// K2: blocks 0..255: softmax (8 d's), e, disease dm-half, medicine partials.
//     block 256: combine mean partials -> dia/med vectors.
__global__ void __launch_bounds__(256) K2(
        const float* __restrict__ W_conv, const float* __restrict__ b_conv,
        const float* __restrict__ b_gat, float* __restrict__ ws,
        float* __restrict__ out) {
    const int b = blockIdx.x, t = threadIdx.x;
    if (b == 256) {
        __shared__ float mc[DIN], mm[DIN];
        float sc = 0.f, sm = 0.f;
        for (int bb = 0; bb < 512; ++bb) sc += ws[WS_PARTC + bb * 256 + t];
        for (int bb = 0; bb < 128; ++bb) sm += ws[WS_PARTM + bb * 256 + t];
        mc[t] = sc * (1.f / ND);
        mm[t] = sm * (1.f / NM);
        __syncthreads();
        if (t < OC) {
            const float4* wr = (const float4*)(W_conv + (size_t)t * DIN);
            float a = 0.f, m2 = 0.f;
#pragma unroll 8
            for (int v = 0; v < 64; ++v) {
                const float4 w = wr[v];
                const int ib = 4 * v;
                a  = fmaf(mc[ib], w.x, a);   a  = fmaf(mc[ib + 1], w.y, a);
                a  = fmaf(mc[ib + 2], w.z, a); a  = fmaf(mc[ib + 3], w.w, a);
                m2 = fmaf(mm[ib], w.x, m2);  m2 = fmaf(mm[ib + 1], w.y, m2);
                m2 = fmaf(mm[ib + 2], w.z, m2); m2 = fmaf(mm[ib + 3], w.w, m2);
            }
            const float bc = b_conv[t];
            ws[WS_DIA + t] = a + bc;
            ws[WS_MED + t] = m2 + bc;
        }
        return;
    }
    __shared__ float zbuf[NE][8];   // alpha (after scaling)
    __shared__ float anm[NM];
    __shared__ float ec[8][OC];     // h1 partial accs, then e values
    anm[t]       = ws[WS_ANODE + ND + t];
    anm[t + 256] = ws[WS_ANODE + ND + 256 + t];
    __syncthreads();
    {
        const int r = t >> 5, l = t & 31;
        const int d = b * 8 + r;
        const float ah = ws[WS_AHE + d];
        const float an_d = ws[WS_ANODE + d];
        float lmax = -3.4e38f;
        for (int j = l; j < NE; j += 32) {
            const float v = (j == 0) ? an_d : anm[j - 1];
            const float lg = lrelu(v + ah);
            zbuf[j][r] = lg;
            lmax = fmaxf(lmax, lg);
        }
#pragma unroll
        for (int m = 1; m < 32; m <<= 1) lmax = fmaxf(lmax, __shfl_xor(lmax, m, 32));
        float ss = 0.f;
        for (int j = l; j < NE; j += 32) {
            const float z = __expf(zbuf[j][r] - lmax);
            zbuf[j][r] = z;
            ss += z;
        }
#pragma unroll
        for (int m = 1; m < 32; m <<= 1) ss += __shfl_xor(ss, m, 32);
        const float inv = 1.f / ss;
        for (int j = l; j < NE; j += 32) zbuf[j][r] *= inv;   // -> alpha
    }
    __syncthreads();
    const int o = t & (OC - 1), h = t >> 7;
    {
        float acc[8] = {0, 0, 0, 0, 0, 0, 0, 0};
        const float* xm = ws + WS_XLIN + (size_t)ND * OC;
        for (int j = h * 256; j < h * 256 + 256; ++j) {
            const float xv = xm[(size_t)j * OC + o];
            const float4* zr = (const float4*)zbuf[j + 1];
            const float4 za = zr[0], zb4 = zr[1];
            acc[0] = fmaf(za.x,  xv, acc[0]);
            acc[1] = fmaf(za.y,  xv, acc[1]);
            acc[2] = fmaf(za.z,  xv, acc[2]);
            acc[3] = fmaf(za.w,  xv, acc[3]);
            acc[4] = fmaf(zb4.x, xv, acc[4]);
            acc[5] = fmaf(zb4.y, xv, acc[5]);
            acc[6] = fmaf(zb4.z, xv, acc[6]);
            acc[7] = fmaf(zb4.w, xv, acc[7]);
        }
        if (h == 1) {
#pragma unroll
            for (int k = 0; k < 8; ++k) ec[k][o] = acc[k];
        }
        __syncthreads();
        if (h == 0) {
            const float bg = b_gat[o];
#pragma unroll
            for (int k = 0; k < 8; ++k) {
                const int dd = b * 8 + k;
                const float a0 = zbuf[0][k];
                const float xown = ws[WS_XLIN + (size_t)dd * OC + o];
                const float ev = fmaf(a0, xown, acc[k] + ec[k][o]) * (1.f / NE);
                ec[k][o] = ev;                                  // stash e for partial pass
                out[(size_t)dd * 2 * OC + o] = fmaf(a0, ev, bg);
                // second half (dia_nf) written by K3
            }
        }
    }
    __syncthreads();
    // medicine partials: part[b][m][o] = sum_k alpha[m+1][k] * e_k[o]
    {
        float* part = ws + WS_PART2 + (size_t)b * NM * OC;
        float ev[8];
#pragma unroll
        for (int k = 0; k < 8; ++k) ev[k] = ec[k][o];
        for (int m = h * 256; m < h * 256 + 256; ++m) {
            const float4* zr = (const float4*)zbuf[m + 1];
            const float4 za = zr[0], zb4 = zr[1];
            float s = za.x * ev[0];
            s = fmaf(za.y,  ev[1], s);
            s = fmaf(za.z,  ev[2], s);
            s = fmaf(za.w,  ev[3], s);
            s = fmaf(zb4.x, ev[4], s);
            s = fmaf(zb4.y, ev[5], s);
            s = fmaf(zb4.z, ev[6], s);
            s = fmaf(zb4.w, ev[7], s);
            part[(size_t)m * OC + o] = s;
        }
    }
}

// ---------------------------------------------------------------------------
// K3: blocks 0..255: medicine rows (sum 256 partials + bias; + med_nf half).
//     blocks 256..319: broadcast dia_nf into disease rows' second half.
__global__ void __launch_bounds__(256) K3(
        const float* __restrict__ b_gat, const float* __restrict__ ws,
        float* __restrict__ out) {
    const int b = blockIdx.x, t = threadIdx.x;
    const int o = t & (OC - 1), h = t >> 7;
    if (b < 256) {
        const int m = 2 * b + h;
        const float* base = ws + WS_PART2 + (size_t)m * OC + o;
        float s = 0.f;
#pragma unroll 8
        for (int b2 = 0; b2 < 256; ++b2) s += base[(size_t)b2 * NM * OC];
        out[(size_t)(ND + m) * 2 * OC + o]      = fmaf(s, 1.f / ND, b_gat[o]);
        out[(size_t)(ND + m) * 2 * OC + OC + o] = ws[WS_MED + o];
    } else {
        const int q = b - 256;
        const float dv = ws[WS_DIA + o];
#pragma unroll
        for (int rr = 0; rr < 16; ++rr) {
            const int d = q * 32 + 2 * rr + h;
            out[(size_t)d * 2 * OC + OC + o] = dv;
        }
    }
}

extern "C" void kernel_launch(void* const* d_in, const int* in_sizes, int n_in,
                              void* d_out, int out_size, void* d_ws, size_t ws_size,
                              hipStream_t stream) {
    const float* c_emb   = (const float*)d_in[2];
    const float* m_emb   = (const float*)d_in[3];
    const float* W_conv  = (const float*)d_in[4];
    const float* b_conv  = (const float*)d_in[5];
    const float* W_gat   = (const float*)d_in[6];
    const float* att     = (const float*)d_in[7];
    const float* b_gat   = (const float*)d_in[8];
    const float* he_attr = (const float*)d_in[9];
    float* ws  = (float*)d_ws;
    float* out = (float*)d_out;

    hipLaunchKernelGGL(K1, dim3(896), dim3(256), 0, stream,
                       c_emb, m_emb, W_gat, att, he_attr, ws);
    hipLaunchKernelGGL(K2, dim3(257), dim3(256), 0, stream,
                       W_conv, b_conv, b_gat, ws, out);
    hipLaunchKernelGGL(K3, dim3(320), dim3(256), 0, stream, b_gat, ws, out);
}

// Round 15
// 151.412 us; speedup vs baseline: 1.9107x; 1.0199x over previous
//
#include <hip/hip_runtime.h>

#define ND 2048
#define NM 512
#define DIN 256
#define OC 128
#define NTOT 2560
#define NE 513      // slots per hyperedge

// Workspace float offsets (total ~500 KB dirty — keeps the harness's 268 MB
// poison-fill fast; R14's 67 MB dirty footprint cost +8.5 µs per fill).
#define WS_PARTC 0                          // [512*256]
#define WS_PARTM (WS_PARTC + 512*256)       // [128*256]
#define WS_AHE   (WS_PARTM + 128*256)       // [2048]
#define WS_ANODE (WS_AHE + ND)              // [2560]
#define WS_CD    (WS_ANODE + NTOT)          // [2048]  C_d = M_d + ln(S_d)
#define WS_XLIN  (WS_CD + ND)               // [2560*128]; disease rows -> e in K2
#define WS_DIA   (WS_XLIN + NTOT*OC)        // [128]
#define WS_MED   (WS_DIA + OC)              // [128]

__device__ __forceinline__ float lrelu(float x) { return x > 0.f ? x : 0.2f * x; }

// ---------------------------------------------------------------------------
// K1: blocks 0..639: x_lin (4 rows) + a_node + mean partials.
//     blocks 640..895: w_e (coalesced, redundant per block) + a_he (8 d's each).
__global__ void __launch_bounds__(256) K1(
        const float* __restrict__ c_emb, const float* __restrict__ m_emb,
        const float* __restrict__ W_gat, const float* __restrict__ att,
        const float* __restrict__ he_attr, float* __restrict__ ws) {
    const int b = blockIdx.x, t = threadIdx.x;
    if (b < 640) {
        __shared__ float row[4][DIN];
        __shared__ float sA[4][OC];
        const int d0 = b * 4;
#pragma unroll
        for (int p = 0; p < 2; ++p) {
            const int idx = p * 256 + t;
            const int r = idx >> 7, c = idx & 127;
            const int d = d0 + r;
            const float* src = (d < ND) ? c_emb + (size_t)d * DIN
                                        : m_emb + (size_t)(d - ND) * DIN;
            const float2 u = ((const float2*)src)[c];
            row[r][2 * c]     = u.x;
            row[r][2 * c + 1] = u.y;
        }
        __syncthreads();
        {
            const float pc = row[0][t] + row[1][t] + row[2][t] + row[3][t];
            if (b < 512) ws[WS_PARTC + b * 256 + t] = pc;
            else         ws[WS_PARTM + (b - 512) * 256 + t] = pc;
        }
        const int o = t & (OC - 1), h = t >> 7;
        float a0 = 0.f, a1 = 0.f;
        const float4* wr = (const float4*)(W_gat + (size_t)o * DIN);
        const float* r0 = row[2 * h];
        const float* r1 = row[2 * h + 1];
#pragma unroll 8
        for (int v = 0; v < 64; ++v) {
            const float4 w = wr[v];
            const int ib = 4 * v;
            a0 = fmaf(r0[ib],     w.x, a0);
            a0 = fmaf(r0[ib + 1], w.y, a0);
            a0 = fmaf(r0[ib + 2], w.z, a0);
            a0 = fmaf(r0[ib + 3], w.w, a0);
            a1 = fmaf(r1[ib],     w.x, a1);
            a1 = fmaf(r1[ib + 1], w.y, a1);
            a1 = fmaf(r1[ib + 2], w.z, a1);
            a1 = fmaf(r1[ib + 3], w.w, a1);
        }
        ws[WS_XLIN + (size_t)(d0 + 2 * h) * OC + o]     = a0;
        ws[WS_XLIN + (size_t)(d0 + 2 * h + 1) * OC + o] = a1;
        const float at = att[o];
        sA[2 * h][o]     = a0 * at;
        sA[2 * h + 1][o] = a1 * at;
        __syncthreads();
#pragma unroll
        for (int st = 64; st >= 1; st >>= 1) {
            if (t < 4 * st) {
                const int r = t / st, i = t - r * st;
                sA[r][i] += sA[r][i + st];
            }
            __syncthreads();
        }
        if (t < 4) ws[WS_ANODE + d0 + t] = sA[t][0];
    } else {
        __shared__ float satt[OC];
        __shared__ float we[DIN];
        const int q = b - 640;
        if (t < OC) satt[t] = att[OC + t];
        __syncthreads();
        float acc = 0.f;
#pragma unroll 8
        for (int o = 0; o < OC; ++o)
            acc = fmaf(W_gat[(size_t)o * DIN + t], satt[o], acc);
        we[t] = acc;
        __syncthreads();
        const int r = t >> 5, l = t & 31;
        const int d = q * 8 + r;
        const float* he = he_attr + (size_t)d * DIN;
        float ah = 0.f;
#pragma unroll
        for (int i = l; i < DIN; i += 32) ah = fmaf(he[i], we[i], ah);
#pragma unroll
        for (int m = 1; m < 32; m <<= 1) ah += __shfl_xor(ah, m, 32);
        if (l == 0) ws[WS_AHE + d] = ah;
    }
}

// ---------------------------------------------------------------------------
// K2: blocks 0..255: softmax (8 d's) -> alpha, C_d; e (in-place over x_lin
//     disease rows); disease dm-half of the output.
//     block 256: combine mean partials -> dia/med vectors.
__global__ void __launch_bounds__(256) K2(
        const float* __restrict__ W_conv, const float* __restrict__ b_conv,
        const float* __restrict__ b_gat, float* __restrict__ ws,
        float* __restrict__ out) {
    const int b = blockIdx.x, t = threadIdx.x;
    if (b == 256) {
        __shared__ float mc[DIN], mm[DIN];
        float sc = 0.f, sm = 0.f;
        for (int bb = 0; bb < 512; ++bb) sc += ws[WS_PARTC + bb * 256 + t];
        for (int bb = 0; bb < 128; ++bb) sm += ws[WS_PARTM + bb * 256 + t];
        mc[t] = sc * (1.f / ND);
        mm[t] = sm * (1.f / NM);
        __syncthreads();
        if (t < OC) {
            const float4* wr = (const float4*)(W_conv + (size_t)t * DIN);
            float a = 0.f, m2 = 0.f;
#pragma unroll 8
            for (int v = 0; v < 64; ++v) {
                const float4 w = wr[v];
                const int ib = 4 * v;
                a  = fmaf(mc[ib], w.x, a);     a  = fmaf(mc[ib + 1], w.y, a);
                a  = fmaf(mc[ib + 2], w.z, a); a  = fmaf(mc[ib + 3], w.w, a);
                m2 = fmaf(mm[ib], w.x, m2);    m2 = fmaf(mm[ib + 1], w.y, m2);
                m2 = fmaf(mm[ib + 2], w.z, m2); m2 = fmaf(mm[ib + 3], w.w, m2);
            }
            const float bc = b_conv[t];
            ws[WS_DIA + t] = a + bc;
            ws[WS_MED + t] = m2 + bc;
        }
        return;
    }
    __shared__ float zbuf[NE][8];   // logits -> z -> alpha
    __shared__ float anm[NM];
    __shared__ float ec[8][OC];
    anm[t]       = ws[WS_ANODE + ND + t];
    anm[t + 256] = ws[WS_ANODE + ND + 256 + t];
    __syncthreads();
    {
        const int r = t >> 5, l = t & 31;
        const int d = b * 8 + r;
        const float ah = ws[WS_AHE + d];
        const float an_d = ws[WS_ANODE + d];
        float lmax = -3.4e38f;
        for (int j = l; j < NE; j += 32) {
            const float v = (j == 0) ? an_d : anm[j - 1];
            const float lg = lrelu(v + ah);
            zbuf[j][r] = lg;
            lmax = fmaxf(lmax, lg);
        }
#pragma unroll
        for (int m = 1; m < 32; m <<= 1) lmax = fmaxf(lmax, __shfl_xor(lmax, m, 32));
        float ss = 0.f;
        for (int j = l; j < NE; j += 32) {
            const float z = __expf(zbuf[j][r] - lmax);
            zbuf[j][r] = z;
            ss += z;
        }
#pragma unroll
        for (int m = 1; m < 32; m <<= 1) ss += __shfl_xor(ss, m, 32);
        const float inv = 1.f / ss;
        if (l == 0) ws[WS_CD + d] = lmax + __logf(ss);   // for K3's alpha recompute
        for (int j = l; j < NE; j += 32) zbuf[j][r] *= inv;   // -> alpha
    }
    __syncthreads();
    const int o = t & (OC - 1), h = t >> 7;
    float acc[8] = {0, 0, 0, 0, 0, 0, 0, 0};
    const float* xm = ws + WS_XLIN + (size_t)ND * OC;
    for (int j = h * 256; j < h * 256 + 256; ++j) {
        const float xv = xm[(size_t)j * OC + o];
        const float4* zr = (const float4*)zbuf[j + 1];
        const float4 za = zr[0], zb4 = zr[1];
        acc[0] = fmaf(za.x,  xv, acc[0]);
        acc[1] = fmaf(za.y,  xv, acc[1]);
        acc[2] = fmaf(za.z,  xv, acc[2]);
        acc[3] = fmaf(za.w,  xv, acc[3]);
        acc[4] = fmaf(zb4.x, xv, acc[4]);
        acc[5] = fmaf(zb4.y, xv, acc[5]);
        acc[6] = fmaf(zb4.z, xv, acc[6]);
        acc[7] = fmaf(zb4.w, xv, acc[7]);
    }
    if (h == 1) {
#pragma unroll
        for (int k = 0; k < 8; ++k) ec[k][o] = acc[k];
    }
    __syncthreads();
    if (h == 0) {
        const float bg = b_gat[o];
#pragma unroll
        for (int k = 0; k < 8; ++k) {
            const int dd = b * 8 + k;
            const float a0 = zbuf[0][k];
            const float xown = ws[WS_XLIN + (size_t)dd * OC + o];
            const float ev = fmaf(a0, xown, acc[k] + ec[k][o]) * (1.f / NE);
            ws[WS_XLIN + (size_t)dd * OC + o] = ev;          // e in-place (own row)
            out[(size_t)dd * 2 * OC + o] = fmaf(a0, ev, bg); // dm half
        }
    }
}

// ---------------------------------------------------------------------------
// K3: blocks 0..255: 2 medicines each over all 2048 diseases (e is 1 MB,
//     L2-resident per XCD). blocks 256..319: dia_nf broadcast into disease rows.
__global__ void __launch_bounds__(256) K3(
        const float* __restrict__ b_gat, const float* __restrict__ ws,
        float* __restrict__ out) {
    const int b = blockIdx.x, t = threadIdx.x;
    const int o = t & (OC - 1), h = t >> 7;
    if (b < 256) {
        __shared__ float zb[ND][2];      // 16 KB
        __shared__ float ec2[2][OC];
        const int m0 = b * 2;
        const float an0 = ws[WS_ANODE + ND + m0];
        const float an1 = ws[WS_ANODE + ND + m0 + 1];
        for (int dd = t; dd < ND; dd += 256) {
            const float ahv = ws[WS_AHE + dd];
            const float cdv = ws[WS_CD + dd];
            zb[dd][0] = __expf(lrelu(an0 + ahv) - cdv);
            zb[dd][1] = __expf(lrelu(an1 + ahv) - cdv);
        }
        __syncthreads();
        float a0 = 0.f, a1 = 0.f;
        const float* e = ws + WS_XLIN;
        for (int dd = h * 1024; dd < h * 1024 + 1024; ++dd) {
            const float ev = e[(size_t)dd * OC + o];
            a0 = fmaf(zb[dd][0], ev, a0);
            a1 = fmaf(zb[dd][1], ev, a1);
        }
        if (h == 1) { ec2[0][o] = a0; ec2[1][o] = a1; }
        __syncthreads();
        if (h == 0) {
            const float bg = b_gat[o];
            const float mv = ws[WS_MED + o];
            out[(size_t)(ND + m0) * 2 * OC + o]          = fmaf(a0 + ec2[0][o], 1.f / ND, bg);
            out[(size_t)(ND + m0) * 2 * OC + OC + o]     = mv;
            out[(size_t)(ND + m0 + 1) * 2 * OC + o]      = fmaf(a1 + ec2[1][o], 1.f / ND, bg);
            out[(size_t)(ND + m0 + 1) * 2 * OC + OC + o] = mv;
        }
    } else {
        const int q = b - 256;
        const float dv = ws[WS_DIA + o];
#pragma unroll
        for (int rr = 0; rr < 16; ++rr) {
            const int d = q * 32 + 2 * rr + h;
            out[(size_t)d * 2 * OC + OC + o] = dv;
        }
    }
}

extern "C" void kernel_launch(void* const* d_in, const int* in_sizes, int n_in,
                              void* d_out, int out_size, void* d_ws, size_t ws_size,
                              hipStream_t stream) {
    const float* c_emb   = (const float*)d_in[2];
    const float* m_emb   = (const float*)d_in[3];
    const float* W_conv  = (const float*)d_in[4];
    const float* b_conv  = (const float*)d_in[5];
    const float* W_gat   = (const float*)d_in[6];
    const float* att     = (const float*)d_in[7];
    const float* b_gat   = (const float*)d_in[8];
    const float* he_attr = (const float*)d_in[9];
    float* ws  = (float*)d_ws;
    float* out = (float*)d_out;

    hipLaunchKernelGGL(K1, dim3(896), dim3(256), 0, stream,
                       c_emb, m_emb, W_gat, att, he_attr, ws);
    hipLaunchKernelGGL(K2, dim3(257), dim3(256), 0, stream,
                       W_conv, b_conv, b_gat, ws, out);
    hipLaunchKernelGGL(K3, dim3(320), dim3(256), 0, stream, b_gat, ws, out);
}